// Round 1
// baseline (27.154 us; speedup 1.0000x reference)
//
#include <hip/hip_runtime.h>

// ConfidanceLoss: iou_gt = windowed-any (5x5x5, zero-clipped) of batchVolume
// sampled at 8^3 cell centers; outputs = [confi, iou_gt, in_use] each [B,512],
// concatenated flat as float32.

constexpr int PN = 512;   // 8^3 cells per batch

__global__ __launch_bounds__(256) void confi_iou_kernel(
    const float* __restrict__ confi,   // [B, 512]
    const int*   __restrict__ vol,     // [B, 32, 32, 32]
    float*       __restrict__ out,     // [3, B, 512] flat
    int B)
{
    const int b = blockIdx.x;
    const int t = threadIdx.x;

    // msh[i2][i1]: 32-bit occupancy mask over i3 for row (i1,i2). +1 pad.
    __shared__ unsigned msh[32][33];
    __shared__ unsigned colOr[8][33];  // colOr[c2][i1]: OR over i2-window
    __shared__ unsigned finOr[8][8];   // finOr[c1][c2]: OR over i1-window

    const int* vb = vol + (size_t)b * 32768;

    // ---- build per-row bitmasks: 32 iterations, one i1-slice each ----
    const int lane7 = t & 7;          // position of this lane's nibble
    const int i2row = t >> 3;         // row (i2) this lane contributes to
    const unsigned shift = lane7 * 4;
    for (int i1 = 0; i1 < 32; ++i1) {
        const int4 v = *reinterpret_cast<const int4*>(vb + i1 * 1024 + t * 4);
        unsigned nib = (v.x != 0 ? 1u : 0u) | (v.y != 0 ? 2u : 0u) |
                       (v.z != 0 ? 4u : 0u) | (v.w != 0 ? 8u : 0u);
        unsigned word = nib << shift;
        word |= __shfl_xor(word, 1);
        word |= __shfl_xor(word, 2);
        word |= __shfl_xor(word, 4);
        if (lane7 == 0) msh[i2row][i1] = word;
    }
    __syncthreads();

    // ---- stage A: reduce i2-window -> colOr[c2][i1] (one entry per thread)
    {
        const int c2 = t >> 5;
        const int i1 = t & 31;
        const int lo = 4 * c2;
        const int hi = (lo + 4 < 31) ? (lo + 4) : 31;
        unsigned acc = 0;
        #pragma unroll
        for (int i2 = lo; i2 <= hi; ++i2) acc |= msh[i2][i1];
        colOr[c2][i1] = acc;
    }
    __syncthreads();

    // ---- stage B: reduce i1-window -> finOr[c1][c2] ----
    if (t < 64) {
        const int c1 = t >> 3;
        const int c2 = t & 7;
        const int lo = 4 * c1;
        const int hi = (lo + 4 < 31) ? (lo + 4) : 31;
        unsigned acc = 0;
        #pragma unroll
        for (int i1 = lo; i1 <= hi; ++i1) acc |= colOr[c2][i1];
        finOr[c1][c2] = acc;
    }
    __syncthreads();

    // ---- emit: j = c3*64 + c2*8 + c1 (c1 = volume dim-1 index, fastest) ----
    const int BP = B * PN;
    #pragma unroll
    for (int j = t; j < PN; j += 256) {
        const int c1 = j & 7;
        const int c2 = (j >> 3) & 7;
        const int c3 = j >> 6;
        const unsigned word = finOr[c1][c2];
        const unsigned bits = (word >> (4 * c3)) & 0x1Fu;  // window [4c3, 4c3+4]
        const float iou = bits ? 1.0f : 0.0f;
        const int idx = b * PN + j;
        out[idx]          = confi[idx];  // output 0: confi pass-through
        out[BP + idx]     = iou;         // output 1: iou_gt
        out[2 * BP + idx] = iou;         // output 2: in_use (read as f32)
    }
}

extern "C" void kernel_launch(void* const* d_in, const int* in_sizes, int n_in,
                              void* d_out, int out_size, void* d_ws, size_t ws_size,
                              hipStream_t stream) {
    // inputs: 0 shape_rlt, 1 trans_rlt, 2 quat_rlt, 3 confi_rlt [B,512,1],
    //         4 batchVolume [B,32,32,32] int32
    const float* confi = (const float*)d_in[3];
    const int*   vol   = (const int*)d_in[4];
    float*       out   = (float*)d_out;
    const int B = in_sizes[4] / 32768;
    confi_iou_kernel<<<B, 256, 0, stream>>>(confi, vol, out, B);
}

// Round 3
// 26.931 us; speedup vs baseline: 1.0082x; 1.0082x over previous
//
#include <hip/hip_runtime.h>

// ConfidanceLoss: iou_gt = windowed-any (5x5x5, zero-clipped) of batchVolume
// sampled at 8^3 cell centers; outputs = [confi, iou_gt, in_use] each [B,512],
// concatenated flat as float32.
//
// R1/R2: 512 threads/block (full 2048 threads/CU occupancy), 2 slices/iter,
// unrolled streaming loads (nontemporal, via clang ext_vector_type so the
// builtin accepts the pointer) to keep more VMEM in flight.

constexpr int PN = 512;   // 8^3 cells per batch

typedef int iv4 __attribute__((ext_vector_type(4)));

__global__ __launch_bounds__(512) void confi_iou_kernel(
    const float* __restrict__ confi,   // [B, 512]
    const int*   __restrict__ vol,     // [B, 32, 32, 32]
    float*       __restrict__ out,     // [3, B, 512] flat
    int B)
{
    const int b = blockIdx.x;
    const int t = threadIdx.x;

    // msh[i2][i1]: 32-bit occupancy mask over i3 for row (i1,i2). +1 pad.
    __shared__ unsigned msh[32][33];
    __shared__ unsigned colOr[8][33];  // colOr[c2][i1]: OR over i2-window
    __shared__ unsigned finOr[8][8];   // finOr[c1][c2]: OR over i1-window

    const int* vb = vol + (size_t)b * 32768;

    // ---- build per-row bitmasks: 16 iterations, two i1-slices each ----
    const int lane7 = t & 7;            // nibble position within the row word
    const int i2row = (t >> 3) & 31;    // row (i2) this lane contributes to
    const int half  = t >> 8;           // which of the 2 slices this thread does
    const unsigned shift = lane7 * 4;

    // per-thread streaming pointer: slice (2*it + half), offset (t&255) int4s
    const iv4* p = reinterpret_cast<const iv4*>(vb) + half * 256 + (t & 255);

    #pragma unroll 4
    for (int it = 0; it < 16; ++it) {
        const iv4 v = __builtin_nontemporal_load(p + it * 512);
        unsigned nib = (v.x != 0 ? 1u : 0u) | (v.y != 0 ? 2u : 0u) |
                       (v.z != 0 ? 4u : 0u) | (v.w != 0 ? 8u : 0u);
        unsigned word = nib << shift;
        word |= __shfl_xor(word, 1);
        word |= __shfl_xor(word, 2);
        word |= __shfl_xor(word, 4);
        if (lane7 == 0) msh[i2row][it * 2 + half] = word;
    }
    __syncthreads();

    // ---- stage A: reduce i2-window -> colOr[c2][i1] ----
    if (t < 256) {
        const int c2 = t >> 5;
        const int i1 = t & 31;
        const int lo = 4 * c2;
        const int hi = (lo + 4 < 31) ? (lo + 4) : 31;
        unsigned acc = 0;
        #pragma unroll
        for (int i2 = lo; i2 <= hi; ++i2) acc |= msh[i2][i1];
        colOr[c2][i1] = acc;
    }
    __syncthreads();

    // ---- stage B: reduce i1-window -> finOr[c1][c2] ----
    if (t < 64) {
        const int c1 = t >> 3;
        const int c2 = t & 7;
        const int lo = 4 * c1;
        const int hi = (lo + 4 < 31) ? (lo + 4) : 31;
        unsigned acc = 0;
        #pragma unroll
        for (int i1 = lo; i1 <= hi; ++i1) acc |= colOr[c2][i1];
        finOr[c1][c2] = acc;
    }
    __syncthreads();

    // ---- emit: j = c3*64 + c2*8 + c1 (c1 = volume dim-1 index, fastest) ----
    {
        const int j = t;                 // 512 threads = 512 cells
        const int c1 = j & 7;
        const int c2 = (j >> 3) & 7;
        const int c3 = j >> 6;
        const unsigned word = finOr[c1][c2];
        const unsigned bits = (word >> (4 * c3)) & 0x1Fu;  // window [4c3, 4c3+4]
        const float iou = bits ? 1.0f : 0.0f;
        const int BP = B * PN;
        const int idx = b * PN + j;
        out[idx]          = confi[idx];  // output 0: confi pass-through
        out[BP + idx]     = iou;         // output 1: iou_gt
        out[2 * BP + idx] = iou;         // output 2: in_use (read as f32)
    }
}

extern "C" void kernel_launch(void* const* d_in, const int* in_sizes, int n_in,
                              void* d_out, int out_size, void* d_ws, size_t ws_size,
                              hipStream_t stream) {
    // inputs: 0 shape_rlt, 1 trans_rlt, 2 quat_rlt, 3 confi_rlt [B,512,1],
    //         4 batchVolume [B,32,32,32] int32
    const float* confi = (const float*)d_in[3];
    const int*   vol   = (const int*)d_in[4];
    float*       out   = (float*)d_out;
    const int B = in_sizes[4] / 32768;
    confi_iou_kernel<<<B, 512, 0, stream>>>(confi, vol, out, B);
}